// Round 1
// baseline (423.840 us; speedup 1.0000x reference)
//
#include <hip/hip_runtime.h>

typedef float  f32x4  __attribute__((ext_vector_type(4)));
typedef __bf16 bf16x8 __attribute__((ext_vector_type(8)));

#define D_MODEL 512
#define SEQ     2048
#define BATCH   8
#define ROWS    (BATCH * SEQ)   // 16384

// ---------------------------------------------------------------- converts
__global__ void cvt_bf16_kernel(const float* __restrict__ in,
                                __bf16* __restrict__ out, int n) {
  int i = blockIdx.x * 256 + threadIdx.x;
  if (i < n) out[i] = (__bf16)in[i];
}

__global__ void exp_bf16_kernel(const float* __restrict__ in,
                                __bf16* __restrict__ out, int n) {
  int i = blockIdx.x * 256 + threadIdx.x;
  if (i < n) out[i] = (__bf16)__expf(in[i]);
}

// ---------------------------------------------------------------- GEMM (NT)
// C[M,Nn] = A[M,K] * Bt[Nn,K]^T (+ bias[col]); EPI: 0=sigmoid(x+b), 1=x+b, 2=x
// 64x64 tile, BK=32, 4 waves (each wave: 16 rows x 64 cols, 4 accumulators).
// LDS row stride 56 bf16 (112 B): conflict-free-ish b128 reads, 16B aligned.
template<int EPI>
__global__ __launch_bounds__(256) void gemm_bt_kernel(
    const __bf16* __restrict__ A, const __bf16* __restrict__ Bt,
    const float* __restrict__ bias, __bf16* __restrict__ C,
    int M, int Nn, int K, long long sB, long long sC)
{
  __shared__ __align__(16) __bf16 As[64][56];
  __shared__ __align__(16) __bf16 Bs[64][56];

  const int b = blockIdx.z;
  Bt += (long long)b * sB;
  C  += (long long)b * sC;

  const int tid  = threadIdx.x;
  const int wave = tid >> 6;
  const int lane = tid & 63;
  const int quad = lane >> 4;   // 0..3
  const int l16  = lane & 15;   // 0..15
  const int m0 = blockIdx.x * 64;
  const int n0 = blockIdx.y * 64;

  // staging: 256 threads x 8 bf16 (16B) = 64x32 tile
  const int lrow = tid >> 2;          // 0..63
  const int lcol = (tid & 3) << 3;    // 0,8,16,24
  const __bf16* ga = A  + (long long)(m0 + lrow) * K + lcol;
  const __bf16* gb = Bt + (long long)(n0 + lrow) * K + lcol;

  f32x4 acc[4];
  #pragma unroll
  for (int j = 0; j < 4; ++j) acc[j] = (f32x4){0.f, 0.f, 0.f, 0.f};

  for (int k0 = 0; k0 < K; k0 += 32) {
    uint4 va = *(const uint4*)(ga + k0);
    uint4 vb = *(const uint4*)(gb + k0);
    *(uint4*)&As[lrow][lcol] = va;
    *(uint4*)&Bs[lrow][lcol] = vb;
    __syncthreads();

    bf16x8 af = *(const bf16x8*)&As[wave * 16 + l16][quad * 8];
    #pragma unroll
    for (int j = 0; j < 4; ++j) {
      bf16x8 bfr = *(const bf16x8*)&Bs[j * 16 + l16][quad * 8];
      acc[j] = __builtin_amdgcn_mfma_f32_16x16x32_bf16(af, bfr, acc[j], 0, 0, 0);
    }
    __syncthreads();
  }

  // epilogue: C/D layout col = lane&15, row = quad*4 + reg
  #pragma unroll
  for (int j = 0; j < 4; ++j) {
    const int col = n0 + j * 16 + l16;
    const float bv = (EPI == 2) ? 0.f : bias[col];
    #pragma unroll
    for (int r = 0; r < 4; ++r) {
      const int row = m0 + wave * 16 + quad * 4 + r;
      float x = acc[j][r] + bv;
      if (EPI == 0) x = 1.f / (1.f + __expf(-x));
      C[(long long)row * Nn + col] = (__bf16)x;
    }
  }
}

// ------------------------------------------------- transform + transpose
// in : kb,vb [BATCH][SEQ][D] bf16 (k,v with bias applied)
// out: ekvT [BATCH][2*D][SEQ] bf16; row d = exp(k)*v, row D+d = exp(k)
__global__ __launch_bounds__(256) void transform_transpose_kernel(
    const __bf16* __restrict__ kb, const __bf16* __restrict__ vb,
    __bf16* __restrict__ ekvT)
{
  __shared__ float t_ekv[32][33];
  __shared__ float t_ek[32][33];
  const int b  = blockIdx.z;
  const int s0 = blockIdx.x * 32;
  const int d0 = blockIdx.y * 32;
  const int tx = threadIdx.x;   // 0..31
  const int ty = threadIdx.y;   // 0..7
  const __bf16* kp = kb + (long long)b * SEQ * D_MODEL;
  const __bf16* vp = vb + (long long)b * SEQ * D_MODEL;

  #pragma unroll
  for (int i = 0; i < 32; i += 8) {
    const int s = s0 + ty + i;
    float kk = (float)kp[(long long)s * D_MODEL + d0 + tx];
    float vv = (float)vp[(long long)s * D_MODEL + d0 + tx];
    float ek = __expf(kk);
    t_ek[ty + i][tx]  = ek;
    t_ekv[ty + i][tx] = ek * vv;
  }
  __syncthreads();

  __bf16* outp = ekvT + (long long)b * (2 * D_MODEL) * SEQ;
  #pragma unroll
  for (int i = 0; i < 32; i += 8) {
    const int d = d0 + ty + i;
    outp[(long long)d * SEQ + s0 + tx]             = (__bf16)t_ekv[tx][ty + i];
    outp[(long long)(D_MODEL + d) * SEQ + s0 + tx] = (__bf16)t_ek[tx][ty + i];
  }
}

// ---------------------------------------------------------------- final
// out[b][t][d] = sigq[b][t][d] * num/den ; out2 [BATCH][SEQ][2*D] bf16
__global__ __launch_bounds__(256) void final_kernel(
    const __bf16* __restrict__ sigq, const __bf16* __restrict__ out2,
    float* __restrict__ out)
{
  int i = blockIdx.x * 256 + threadIdx.x;   // over ROWS*D = 8.4M
  if (i >= ROWS * D_MODEL) return;
  int d = i & (D_MODEL - 1);
  int bt = i >> 9;                          // /512
  float num = (float)out2[(long long)bt * (2 * D_MODEL) + d];
  float den = (float)out2[(long long)bt * (2 * D_MODEL) + D_MODEL + d];
  float s   = (float)sigq[i];
  out[i] = s * (num / den);
}

// ---------------------------------------------------------------- launch
extern "C" void kernel_launch(void* const* d_in, const int* in_sizes, int n_in,
                              void* d_out, int out_size, void* d_ws, size_t ws_size,
                              hipStream_t stream) {
  const float* inputs1 = (const float*)d_in[0];
  const float* inputs2 = (const float*)d_in[1];
  const float* Wq = (const float*)d_in[2];
  const float* bq = (const float*)d_in[3];
  const float* Wk = (const float*)d_in[4];
  const float* bk = (const float*)d_in[5];
  const float* Wv = (const float*)d_in[6];
  const float* bv = (const float*)d_in[7];
  const float* posb = (const float*)d_in[8];
  float* out = (float*)d_out;

  // workspace layout (bytes)
  char* ws = (char*)d_ws;
  const long long szX  = (long long)ROWS * D_MODEL * 2;        // 16.78 MB
  const long long szW  = (long long)D_MODEL * D_MODEL * 2;     // 0.52 MB
  const long long szEB = (long long)SEQ * SEQ * 2;             // 8.39 MB
  const long long szT  = (long long)BATCH * 2 * D_MODEL * SEQ * 2; // 33.55 MB
  __bf16* x1b   = (__bf16*)(ws);                 ws += szX;
  __bf16* x2b   = (__bf16*)(ws);                 ws += szX;
  __bf16* wqb   = (__bf16*)(ws);                 ws += szW;
  __bf16* wkb   = (__bf16*)(ws);                 ws += szW;
  __bf16* wvb   = (__bf16*)(ws);                 ws += szW;
  __bf16* expBb = (__bf16*)(ws);                 ws += szEB;
  __bf16* sigq  = (__bf16*)(ws);                 ws += szX;
  __bf16* kb2   = (__bf16*)(ws);                 ws += szX;
  __bf16* vb2   = (__bf16*)(ws);                 ws += szX;
  __bf16* ekvT  = (__bf16*)(ws);                 ws += szT;
  __bf16* out2  = (__bf16*)(ws);                 ws += szT;

  const int nX  = ROWS * D_MODEL;      // 8388608
  const int nW  = D_MODEL * D_MODEL;   // 262144
  const int nEB = SEQ * SEQ;           // 4194304

  // 1) convert
  cvt_bf16_kernel<<<(nX + 255) / 256, 256, 0, stream>>>(inputs1, x1b, nX);
  cvt_bf16_kernel<<<(nX + 255) / 256, 256, 0, stream>>>(inputs2, x2b, nX);
  cvt_bf16_kernel<<<(nW + 255) / 256, 256, 0, stream>>>(Wq, wqb, nW);
  cvt_bf16_kernel<<<(nW + 255) / 256, 256, 0, stream>>>(Wk, wkb, nW);
  cvt_bf16_kernel<<<(nW + 255) / 256, 256, 0, stream>>>(Wv, wvb, nW);
  exp_bf16_kernel<<<(nEB + 255) / 256, 256, 0, stream>>>(posb, expBb, nEB);

  // 2) projections: [16384,512] x [512,512]^T
  {
    dim3 g(ROWS / 64, D_MODEL / 64, 1);
    gemm_bt_kernel<0><<<g, 256, 0, stream>>>(x1b, wqb, bq, sigq,
        ROWS, D_MODEL, D_MODEL, 0LL, 0LL);
    gemm_bt_kernel<1><<<g, 256, 0, stream>>>(x1b, wkb, bk, kb2,
        ROWS, D_MODEL, D_MODEL, 0LL, 0LL);
    gemm_bt_kernel<1><<<g, 256, 0, stream>>>(x2b, wvb, bv, vb2,
        ROWS, D_MODEL, D_MODEL, 0LL, 0LL);
  }

  // 3) transform + transpose -> ekvT [b][2D][S]
  {
    dim3 g(SEQ / 32, D_MODEL / 32, BATCH);
    dim3 blk(32, 8, 1);
    transform_transpose_kernel<<<g, blk, 0, stream>>>(kb2, vb2, ekvT);
  }

  // 4) einsum: per batch [2048,2048] x [1024,2048]^T -> out2 [b][S][2D]
  {
    dim3 g(SEQ / 64, (2 * D_MODEL) / 64, BATCH);
    gemm_bt_kernel<2><<<g, 256, 0, stream>>>(expBb, ekvT, nullptr, out2,
        SEQ, 2 * D_MODEL, SEQ,
        (long long)(2 * D_MODEL) * SEQ, (long long)SEQ * (2 * D_MODEL));
  }

  // 5) final
  final_kernel<<<(nX + 255) / 256, 256, 0, stream>>>(sigq, out2, out);
}

// Round 2
// 335.299 us; speedup vs baseline: 1.2641x; 1.2641x over previous
//
#include <hip/hip_runtime.h>

typedef float  f32x4  __attribute__((ext_vector_type(4)));
typedef __bf16 bf16x8 __attribute__((ext_vector_type(8)));
typedef __bf16 bf16x4 __attribute__((ext_vector_type(4)));

#define D_MODEL 512
#define SEQ     2048
#define BATCH   8
#define ROWS    (BATCH * SEQ)   // 16384

// async 16B global -> LDS (lane deposits at ldsbase + lane*16)
#define ASYNC_COPY16(dst_lds, src_glb)                                          \
  __builtin_amdgcn_global_load_lds(                                             \
      (const __attribute__((address_space(1))) void*)(src_glb),                 \
      (__attribute__((address_space(3))) void*)(dst_lds), 16, 0, 0)

// ---------------------------------------------------------------- converts
__global__ void cvt_bf16x4_kernel(const float* __restrict__ in,
                                  __bf16* __restrict__ out, int n4) {
  int i = blockIdx.x * 256 + threadIdx.x;
  if (i >= n4) return;
  float4 v = ((const float4*)in)[i];
  bf16x4 o = { (__bf16)v.x, (__bf16)v.y, (__bf16)v.z, (__bf16)v.w };
  ((bf16x4*)out)[i] = o;
}

__global__ void exp_bf16x4_kernel(const float* __restrict__ in,
                                  __bf16* __restrict__ out, int n4) {
  int i = blockIdx.x * 256 + threadIdx.x;
  if (i >= n4) return;
  float4 v = ((const float4*)in)[i];
  bf16x4 o = { (__bf16)__expf(v.x), (__bf16)__expf(v.y),
               (__bf16)__expf(v.z), (__bf16)__expf(v.w) };
  ((bf16x4*)out)[i] = o;
}

// ---------------------------------------------------------------- GEMM (NT)
// C[M,Nn] = A[M,K] * Bt[Nn,K]^T (+ bias[col]); EPI: 0=sigmoid(x+b), 1=x+b, 2=x
// m97 structure: 128x128 tile, BK=32, 4 waves in 2x2, each wave 64x64 via
// 4x4 grid of 16x16x32 MFMA. Staging via global_load_lds width=16 (async,
// no VGPR round-trip). LDS unpadded 128x32 row-major (required by the fixed
// lane->LDS mapping of global_load_lds).
template<int EPI>
__global__ __launch_bounds__(256) void gemm128_kernel(
    const __bf16* __restrict__ A, const __bf16* __restrict__ Bt,
    const float* __restrict__ bias, __bf16* __restrict__ C,
    int M, int Nn, int K, long long sB, long long sC)
{
  __shared__ __align__(16) __bf16 As[128 * 32];
  __shared__ __align__(16) __bf16 Bs[128 * 32];

  const int b = blockIdx.z;
  Bt += (long long)b * sB;
  C  += (long long)b * sC;

  const int tid  = threadIdx.x;
  const int wave = tid >> 6;
  const int lane = tid & 63;
  const int quad = lane >> 4;   // 0..3
  const int l16  = lane & 15;   // 0..15
  const int wm   = (wave >> 1) * 64;  // wave row offset within 128-tile
  const int wn   = (wave & 1) * 64;   // wave col offset
  const int m0 = blockIdx.x * 128;
  const int n0 = blockIdx.y * 128;

  // staging: per issue, wave w lane l loads 16B: row = w*16 + (l>>2),
  // col = (l&3)*8 -> LDS offset = lane*16 B from wave base (row-major match)
  const int srow = wave * 16 + (lane >> 2);
  const int scol = (lane & 3) * 8;
  const __bf16* gA0 = A  + (long long)(m0 + srow) * K + scol;
  const __bf16* gA1 = A  + (long long)(m0 + 64 + srow) * K + scol;
  const __bf16* gB0 = Bt + (long long)(n0 + srow) * K + scol;
  const __bf16* gB1 = Bt + (long long)(n0 + 64 + srow) * K + scol;
  __bf16* lA0 = As + wave * 512;          // 64 lanes * 8 elems
  __bf16* lA1 = As + 2048 + wave * 512;   // rows 64..127
  __bf16* lB0 = Bs + wave * 512;
  __bf16* lB1 = Bs + 2048 + wave * 512;

  f32x4 acc[4][4];
  #pragma unroll
  for (int i = 0; i < 4; ++i)
    #pragma unroll
    for (int j = 0; j < 4; ++j) acc[i][j] = (f32x4){0.f, 0.f, 0.f, 0.f};

  for (int k0 = 0; k0 < K; k0 += 32) {
    ASYNC_COPY16(lA0, gA0 + k0);
    ASYNC_COPY16(lA1, gA1 + k0);
    ASYNC_COPY16(lB0, gB0 + k0);
    ASYNC_COPY16(lB1, gB1 + k0);
    __syncthreads();

    bf16x8 af[4], bfr[4];
    #pragma unroll
    for (int i = 0; i < 4; ++i)
      af[i] = *(const bf16x8*)&As[(wm + i * 16 + l16) * 32 + quad * 8];
    #pragma unroll
    for (int j = 0; j < 4; ++j)
      bfr[j] = *(const bf16x8*)&Bs[(wn + j * 16 + l16) * 32 + quad * 8];

    #pragma unroll
    for (int i = 0; i < 4; ++i)
      #pragma unroll
      for (int j = 0; j < 4; ++j)
        acc[i][j] = __builtin_amdgcn_mfma_f32_16x16x32_bf16(af[i], bfr[j],
                                                            acc[i][j], 0, 0, 0);
    __syncthreads();
  }

  // epilogue: C/D layout col = lane&15, row = quad*4 + reg
  #pragma unroll
  for (int j = 0; j < 4; ++j) {
    const int col = n0 + wn + j * 16 + l16;
    const float bv = (EPI == 2) ? 0.f : bias[col];
    #pragma unroll
    for (int i = 0; i < 4; ++i) {
      #pragma unroll
      for (int r = 0; r < 4; ++r) {
        const int row = m0 + wm + i * 16 + quad * 4 + r;
        float x = acc[i][j][r] + bv;
        if (EPI == 0) x = 1.f / (1.f + __expf(-x));
        C[(long long)row * Nn + col] = (__bf16)x;
      }
    }
  }
}

// ------------------------------------------------- transform + transpose
// in : kb,vb [BATCH][SEQ][D] bf16 (k,v with bias applied)
// out: ekvT [BATCH][2*D][SEQ] bf16; row d = exp(k)*v, row D+d = exp(k)
__global__ __launch_bounds__(256) void transform_transpose_kernel(
    const __bf16* __restrict__ kb, const __bf16* __restrict__ vb,
    __bf16* __restrict__ ekvT)
{
  __shared__ float t_ekv[32][33];
  __shared__ float t_ek[32][33];
  const int b  = blockIdx.z;
  const int s0 = blockIdx.x * 32;
  const int d0 = blockIdx.y * 32;
  const int tx = threadIdx.x;   // 0..31
  const int ty = threadIdx.y;   // 0..7
  const __bf16* kp = kb + (long long)b * SEQ * D_MODEL;
  const __bf16* vp = vb + (long long)b * SEQ * D_MODEL;

  #pragma unroll
  for (int i = 0; i < 32; i += 8) {
    const int s = s0 + ty + i;
    float kk = (float)kp[(long long)s * D_MODEL + d0 + tx];
    float vv = (float)vp[(long long)s * D_MODEL + d0 + tx];
    float ek = __expf(kk);
    t_ek[ty + i][tx]  = ek;
    t_ekv[ty + i][tx] = ek * vv;
  }
  __syncthreads();

  __bf16* outp = ekvT + (long long)b * (2 * D_MODEL) * SEQ;
  #pragma unroll
  for (int i = 0; i < 32; i += 8) {
    const int d = d0 + ty + i;
    outp[(long long)d * SEQ + s0 + tx]             = (__bf16)t_ekv[tx][ty + i];
    outp[(long long)(D_MODEL + d) * SEQ + s0 + tx] = (__bf16)t_ek[tx][ty + i];
  }
}

// ---------------------------------------------------------------- final
// out[b][t][d] = sigq[b][t][d] * num/den ; out2 [BATCH][SEQ][2*D] bf16
__global__ __launch_bounds__(256) void final_kernel(
    const __bf16* __restrict__ sigq, const __bf16* __restrict__ out2,
    float* __restrict__ out)
{
  int i = blockIdx.x * 256 + threadIdx.x;   // over ROWS*D/4
  if (i >= ROWS * D_MODEL / 4) return;
  int d4 = (i & 127) << 2;                  // 4 consecutive d in 0..511
  int bt = i >> 7;
  const __bf16* np = out2 + (long long)bt * (2 * D_MODEL) + d4;
  bf16x4 num = *(const bf16x4*)np;
  bf16x4 den = *(const bf16x4*)(np + D_MODEL);
  bf16x4 s   = ((const bf16x4*)sigq)[i];
  float4 o;
  o.x = (float)s[0] * ((float)num[0] / (float)den[0]);
  o.y = (float)s[1] * ((float)num[1] / (float)den[1]);
  o.z = (float)s[2] * ((float)num[2] / (float)den[2]);
  o.w = (float)s[3] * ((float)num[3] / (float)den[3]);
  ((float4*)out)[i] = o;
}

// ---------------------------------------------------------------- launch
extern "C" void kernel_launch(void* const* d_in, const int* in_sizes, int n_in,
                              void* d_out, int out_size, void* d_ws, size_t ws_size,
                              hipStream_t stream) {
  const float* inputs1 = (const float*)d_in[0];
  const float* inputs2 = (const float*)d_in[1];
  const float* Wq = (const float*)d_in[2];
  const float* bq = (const float*)d_in[3];
  const float* Wk = (const float*)d_in[4];
  const float* bk = (const float*)d_in[5];
  const float* Wv = (const float*)d_in[6];
  const float* bv = (const float*)d_in[7];
  const float* posb = (const float*)d_in[8];
  float* out = (float*)d_out;

  // workspace layout (bytes)
  char* ws = (char*)d_ws;
  const long long szX  = (long long)ROWS * D_MODEL * 2;            // 16.78 MB
  const long long szW  = (long long)D_MODEL * D_MODEL * 2;         // 0.52 MB
  const long long szEB = (long long)SEQ * SEQ * 2;                 // 8.39 MB
  const long long szT  = (long long)BATCH * 2 * D_MODEL * SEQ * 2; // 33.55 MB
  __bf16* x1b   = (__bf16*)(ws);                 ws += szX;
  __bf16* x2b   = (__bf16*)(ws);                 ws += szX;
  __bf16* wqb   = (__bf16*)(ws);                 ws += szW;
  __bf16* wkb   = (__bf16*)(ws);                 ws += szW;
  __bf16* wvb   = (__bf16*)(ws);                 ws += szW;
  __bf16* expBb = (__bf16*)(ws);                 ws += szEB;
  __bf16* sigq  = (__bf16*)(ws);                 ws += szX;
  __bf16* kb2   = (__bf16*)(ws);                 ws += szX;
  __bf16* vb2   = (__bf16*)(ws);                 ws += szX;
  __bf16* ekvT  = (__bf16*)(ws);                 ws += szT;
  __bf16* out2  = (__bf16*)(ws);                 ws += szT;

  const int nX  = ROWS * D_MODEL;      // 8388608
  const int nW  = D_MODEL * D_MODEL;   // 262144
  const int nEB = SEQ * SEQ;           // 4194304

  // 1) convert (vectorized x4)
  cvt_bf16x4_kernel<<<nX / 4 / 256, 256, 0, stream>>>(inputs1, x1b, nX / 4);
  cvt_bf16x4_kernel<<<nX / 4 / 256, 256, 0, stream>>>(inputs2, x2b, nX / 4);
  cvt_bf16x4_kernel<<<nW / 4 / 256, 256, 0, stream>>>(Wq, wqb, nW / 4);
  cvt_bf16x4_kernel<<<nW / 4 / 256, 256, 0, stream>>>(Wk, wkb, nW / 4);
  cvt_bf16x4_kernel<<<nW / 4 / 256, 256, 0, stream>>>(Wv, wvb, nW / 4);
  exp_bf16x4_kernel<<<nEB / 4 / 256, 256, 0, stream>>>(posb, expBb, nEB / 4);

  // 2) projections: [16384,512] x [512,512]^T, 128-tile
  {
    dim3 g(ROWS / 128, D_MODEL / 128, 1);
    gemm128_kernel<0><<<g, 256, 0, stream>>>(x1b, wqb, bq, sigq,
        ROWS, D_MODEL, D_MODEL, 0LL, 0LL);
    gemm128_kernel<1><<<g, 256, 0, stream>>>(x1b, wkb, bk, kb2,
        ROWS, D_MODEL, D_MODEL, 0LL, 0LL);
    gemm128_kernel<1><<<g, 256, 0, stream>>>(x2b, wvb, bv, vb2,
        ROWS, D_MODEL, D_MODEL, 0LL, 0LL);
  }

  // 3) transform + transpose -> ekvT [b][2D][S]
  {
    dim3 g(SEQ / 32, D_MODEL / 32, BATCH);
    dim3 blk(32, 8, 1);
    transform_transpose_kernel<<<g, blk, 0, stream>>>(kb2, vb2, ekvT);
  }

  // 4) einsum: per batch [2048,2048] x [1024,2048]^T -> out2 [b][S][2D]
  {
    dim3 g(SEQ / 128, (2 * D_MODEL) / 128, BATCH);
    gemm128_kernel<2><<<g, 256, 0, stream>>>(expBb, ekvT, nullptr, out2,
        SEQ, 2 * D_MODEL, SEQ,
        (long long)(2 * D_MODEL) * SEQ, (long long)SEQ * (2 * D_MODEL));
  }

  // 5) final (vectorized x4)
  final_kernel<<<nX / 4 / 256, 256, 0, stream>>>(sigq, out2, out);
}

// Round 3
// 277.131 us; speedup vs baseline: 1.5294x; 1.2099x over previous
//
#include <hip/hip_runtime.h>

typedef float  f32x4  __attribute__((ext_vector_type(4)));
typedef __bf16 bf16x8 __attribute__((ext_vector_type(8)));
typedef __bf16 bf16x4 __attribute__((ext_vector_type(4)));
typedef __bf16 bf16x2 __attribute__((ext_vector_type(2)));

#define D_MODEL 512
#define SEQ     2048
#define BATCH   8
#define ROWS    (BATCH * SEQ)   // 16384

// async 16B global -> LDS (each lane deposits at lds_base + lane*16B)
#define ASYNC_COPY16(dst_lds, src_glb)                                          \
  __builtin_amdgcn_global_load_lds(                                             \
      (const __attribute__((address_space(1))) void*)(src_glb),                 \
      (__attribute__((address_space(3))) void*)(dst_lds), 16, 0, 0)

// ---------------------------------------------------------------- converts
// y=0: in0->o0 ; y=1: in1->o1   (x4 vectorized)
__global__ void cvt_x_kernel(const float* __restrict__ in0,
                             const float* __restrict__ in1,
                             __bf16* __restrict__ o0, __bf16* __restrict__ o1,
                             int n4) {
  const float* in = blockIdx.y ? in1 : in0;
  __bf16* out = blockIdx.y ? o1 : o0;
  int i = blockIdx.x * 256 + threadIdx.x;
  if (i >= n4) return;
  float4 v = ((const float4*)in)[i];
  bf16x4 o = { (__bf16)v.x, (__bf16)v.y, (__bf16)v.z, (__bf16)v.w };
  ((bf16x4*)out)[i] = o;
}

// weights: y=0 Wq->wqk[0:], y=1 Wk->wqk[nW:], y=2 Wv->wvb; also concat biases
__global__ void cvt_w_kernel(const float* __restrict__ Wq,
                             const float* __restrict__ Wk,
                             const float* __restrict__ Wv,
                             const float* __restrict__ bq,
                             const float* __restrict__ bk,
                             __bf16* __restrict__ wqk, __bf16* __restrict__ wvb,
                             float* __restrict__ bqk, int n4) {
  const int y = blockIdx.y;
  const float* in = (y == 0) ? Wq : (y == 1) ? Wk : Wv;
  __bf16* out = (y == 0) ? wqk : (y == 1) ? (wqk + n4 * 4) : wvb;
  int i = blockIdx.x * 256 + threadIdx.x;
  if (y < 2 && blockIdx.x == 0 && threadIdx.x < D_MODEL) {
    int t = threadIdx.x;
    bqk[y * D_MODEL + t] = (y == 0) ? bq[t] : bk[t];
  }
  if (i >= n4) return;
  float4 v = ((const float4*)in)[i];
  bf16x4 o = { (__bf16)v.x, (__bf16)v.y, (__bf16)v.z, (__bf16)v.w };
  ((bf16x4*)out)[i] = o;
}

__global__ void exp_bf16x4_kernel(const float* __restrict__ in,
                                  __bf16* __restrict__ out, int n4) {
  int i = blockIdx.x * 256 + threadIdx.x;
  if (i >= n4) return;
  float4 v = ((const float4*)in)[i];
  bf16x4 o = { (__bf16)__expf(v.x), (__bf16)__expf(v.y),
               (__bf16)__expf(v.z), (__bf16)__expf(v.w) };
  ((bf16x4*)out)[i] = o;
}

// ---------------------------------------------------------------- GEMM core
// 128x128 tile, BK=64, 4 waves in 2x2, 16x16x32 MFMA, XOR-swizzled staging.
// Staging: issue i covers rows i*32+wave*8+(lane>>3); lane stores 16B at
// slot lane&7; SOURCE chunk = (lane&7)^(lane>>3). Reader slot = chunk^(row&7).
// Result: every 8-lane LDS phase hits distinct banks (2-way max = free).

// DUAL=1: N=1024 = [Wq;Wk]-proj: col<512 -> sigmoid -> out0; else plain -> out1
// DUAL=0: plain bf16 -> out0 (pitch = D_MODEL)
template<int DUAL>
__global__ __launch_bounds__(256) void gemm_bk64_kernel(
    const __bf16* __restrict__ A, const __bf16* __restrict__ Bt,
    const float* __restrict__ bias,
    __bf16* __restrict__ out0, __bf16* __restrict__ out1, int K)
{
  __shared__ __align__(16) __bf16 As[128 * 64];
  __shared__ __align__(16) __bf16 Bs[128 * 64];

  const int tid  = threadIdx.x;
  const int wave = tid >> 6;
  const int lane = tid & 63;
  const int quad = lane >> 4;
  const int l16  = lane & 15;
  const int wm   = (wave >> 1) * 64;
  const int wn   = (wave & 1) * 64;
  const int m0 = blockIdx.x * 128;
  const int n0 = blockIdx.y * 128;
  const int l8r = lane >> 3;
  const int scol = ((lane & 7) ^ l8r) * 8;

  const __bf16* ga[4]; const __bf16* gb[4];
  __bf16* la[4]; __bf16* lb[4];
  #pragma unroll
  for (int i = 0; i < 4; ++i) {
    ga[i] = A  + (long long)(m0 + i * 32 + wave * 8 + l8r) * K + scol;
    gb[i] = Bt + (long long)(n0 + i * 32 + wave * 8 + l8r) * K + scol;
    la[i] = As + (i * 32 + wave * 8) * 64;
    lb[i] = Bs + (i * 32 + wave * 8) * 64;
  }

  f32x4 acc[4][4];
  #pragma unroll
  for (int i = 0; i < 4; ++i)
    #pragma unroll
    for (int j = 0; j < 4; ++j) acc[i][j] = (f32x4){0.f, 0.f, 0.f, 0.f};

  for (int k0 = 0; k0 < K; k0 += 64) {
    #pragma unroll
    for (int i = 0; i < 4; ++i) {
      ASYNC_COPY16(la[i], ga[i] + k0);
      ASYNC_COPY16(lb[i], gb[i] + k0);
    }
    __syncthreads();

    #pragma unroll
    for (int kk = 0; kk < 2; ++kk) {
      const int slot = ((quad + kk * 4) ^ (l16 & 7)) * 8;
      bf16x8 af[4], bfr[4];
      #pragma unroll
      for (int i = 0; i < 4; ++i)
        af[i] = *(const bf16x8*)&As[(wm + i * 16 + l16) * 64 + slot];
      #pragma unroll
      for (int j = 0; j < 4; ++j)
        bfr[j] = *(const bf16x8*)&Bs[(wn + j * 16 + l16) * 64 + slot];
      #pragma unroll
      for (int i = 0; i < 4; ++i)
        #pragma unroll
        for (int j = 0; j < 4; ++j)
          acc[i][j] = __builtin_amdgcn_mfma_f32_16x16x32_bf16(af[i], bfr[j],
                                                              acc[i][j], 0, 0, 0);
    }
    __syncthreads();
  }

  // epilogue: C/D layout col = lane&15, row = quad*4 + reg
  #pragma unroll
  for (int j = 0; j < 4; ++j) {
    const int col = n0 + wn + j * 16 + l16;
    const float bv = bias[col];
    #pragma unroll
    for (int i = 0; i < 4; ++i) {
      #pragma unroll
      for (int r = 0; r < 4; ++r) {
        const int row = m0 + wm + i * 16 + quad * 4 + r;
        float x = acc[i][j][r] + bv;
        if (DUAL) {
          if (col < D_MODEL) {
            out0[(long long)row * D_MODEL + col] = (__bf16)(1.f / (1.f + __expf(-x)));
          } else {
            out1[(long long)row * D_MODEL + (col - D_MODEL)] = (__bf16)x;
          }
        } else {
          out0[(long long)row * D_MODEL + col] = (__bf16)x;
        }
      }
    }
  }
}

// -------------------------------------------- einsum + final, fused epilogue
// A = expB [2048][2048]; Bt = ekvT grouped [BATCH][1024][2048] where group g
// (32 d's): rows g*64+w = ekv(d=g*32+w), rows g*64+32+w = ek(same d).
// Within a wave (64 cols): acc[i][j] j<2 = num(d), acc[i][j+2] = den(same d).
// out[b*SEQ+t][d] = sigq * num/den  (fp32, written directly).
__global__ __launch_bounds__(256) void einsum_fused_kernel(
    const __bf16* __restrict__ A, const __bf16* __restrict__ BtAll,
    const __bf16* __restrict__ sigq, float* __restrict__ out)
{
  __shared__ __align__(16) __bf16 As[128 * 64];
  __shared__ __align__(16) __bf16 Bs[128 * 64];

  const int b = blockIdx.z;
  const __bf16* Bt = BtAll + (long long)b * (2 * D_MODEL) * SEQ;
  const int K = SEQ;

  const int tid  = threadIdx.x;
  const int wave = tid >> 6;
  const int lane = tid & 63;
  const int quad = lane >> 4;
  const int l16  = lane & 15;
  const int wm   = (wave >> 1) * 64;
  const int wn   = (wave & 1) * 64;
  const int m0 = blockIdx.x * 128;
  const int n0 = blockIdx.y * 128;
  const int l8r = lane >> 3;
  const int scol = ((lane & 7) ^ l8r) * 8;

  const __bf16* ga[4]; const __bf16* gb[4];
  __bf16* la[4]; __bf16* lb[4];
  #pragma unroll
  for (int i = 0; i < 4; ++i) {
    ga[i] = A  + (long long)(m0 + i * 32 + wave * 8 + l8r) * K + scol;
    gb[i] = Bt + (long long)(n0 + i * 32 + wave * 8 + l8r) * K + scol;
    la[i] = As + (i * 32 + wave * 8) * 64;
    lb[i] = Bs + (i * 32 + wave * 8) * 64;
  }

  f32x4 acc[4][4];
  #pragma unroll
  for (int i = 0; i < 4; ++i)
    #pragma unroll
    for (int j = 0; j < 4; ++j) acc[i][j] = (f32x4){0.f, 0.f, 0.f, 0.f};

  for (int k0 = 0; k0 < K; k0 += 64) {
    #pragma unroll
    for (int i = 0; i < 4; ++i) {
      ASYNC_COPY16(la[i], ga[i] + k0);
      ASYNC_COPY16(lb[i], gb[i] + k0);
    }
    __syncthreads();

    #pragma unroll
    for (int kk = 0; kk < 2; ++kk) {
      const int slot = ((quad + kk * 4) ^ (l16 & 7)) * 8;
      bf16x8 af[4], bfr[4];
      #pragma unroll
      for (int i = 0; i < 4; ++i)
        af[i] = *(const bf16x8*)&As[(wm + i * 16 + l16) * 64 + slot];
      #pragma unroll
      for (int j = 0; j < 4; ++j)
        bfr[j] = *(const bf16x8*)&Bs[(wn + j * 16 + l16) * 64 + slot];
      #pragma unroll
      for (int i = 0; i < 4; ++i)
        #pragma unroll
        for (int j = 0; j < 4; ++j)
          acc[i][j] = __builtin_amdgcn_mfma_f32_16x16x32_bf16(af[i], bfr[j],
                                                              acc[i][j], 0, 0, 0);
    }
    __syncthreads();
  }

  // fused epilogue: g = (n0+wn)/64; j in {0,1}: d = g*32 + j*16 + l16
  const int g = (n0 + wn) >> 6;
  #pragma unroll
  for (int j = 0; j < 2; ++j) {
    const int d = g * 32 + j * 16 + l16;
    #pragma unroll
    for (int i = 0; i < 4; ++i) {
      #pragma unroll
      for (int r = 0; r < 4; ++r) {
        const int row = m0 + wm + i * 16 + quad * 4 + r;
        const long long off = ((long long)b * SEQ + row) * D_MODEL + d;
        const float num = acc[i][j][r];
        const float den = acc[i][j + 2][r];
        out[off] = (float)sigq[off] * (num / den);
      }
    }
  }
}

// ------------------------------------------------- transform + transpose
// in : kb,vb [BATCH][SEQ][D] bf16; out: ekvT grouped [BATCH][1024][SEQ]:
// for d: g=d>>5, w=d&31: row g*64+w = exp(k)*v, row g*64+32+w = exp(k)
__global__ __launch_bounds__(256) void transform_transpose_kernel(
    const __bf16* __restrict__ kb, const __bf16* __restrict__ vb,
    __bf16* __restrict__ ekvT)
{
  __shared__ float t_ekv[64][67];
  __shared__ float t_ek[64][67];
  const int b  = blockIdx.z;
  const int s0 = blockIdx.x * 64;
  const int d0 = blockIdx.y * 64;
  const int tx = threadIdx.x;   // 0..31
  const int ty = threadIdx.y;   // 0..7
  const __bf16* kp = kb + (long long)b * SEQ * D_MODEL;
  const __bf16* vp = vb + (long long)b * SEQ * D_MODEL;

  #pragma unroll
  for (int it = 0; it < 8; ++it) {
    const int sl = ty + it * 8;               // local s row 0..63
    const long long base = (long long)(s0 + sl) * D_MODEL + d0 + 2 * tx;
    bf16x2 kk2 = *(const bf16x2*)(kp + base);
    bf16x2 vv2 = *(const bf16x2*)(vp + base);
    float e0 = __expf((float)kk2[0]);
    float e1 = __expf((float)kk2[1]);
    t_ek[sl][2 * tx]      = e0;
    t_ek[sl][2 * tx + 1]  = e1;
    t_ekv[sl][2 * tx]     = e0 * (float)vv2[0];
    t_ekv[sl][2 * tx + 1] = e1 * (float)vv2[1];
  }
  __syncthreads();

  __bf16* outp = ekvT + (long long)b * (2 * D_MODEL) * SEQ;
  #pragma unroll
  for (int it = 0; it < 8; ++it) {
    const int dl = ty + it * 8;               // local d 0..63
    const int d  = d0 + dl;
    const int gr = (d >> 5) * 64 + (d & 31);  // grouped ekv row
    bf16x2 ev = { (__bf16)t_ekv[2 * tx][dl], (__bf16)t_ekv[2 * tx + 1][dl] };
    bf16x2 ee = { (__bf16)t_ek[2 * tx][dl],  (__bf16)t_ek[2 * tx + 1][dl] };
    *(bf16x2*)(outp + (long long)gr * SEQ + s0 + 2 * tx)        = ev;
    *(bf16x2*)(outp + (long long)(gr + 32) * SEQ + s0 + 2 * tx) = ee;
  }
}

// ---------------------------------------------------------------- launch
extern "C" void kernel_launch(void* const* d_in, const int* in_sizes, int n_in,
                              void* d_out, int out_size, void* d_ws, size_t ws_size,
                              hipStream_t stream) {
  const float* inputs1 = (const float*)d_in[0];
  const float* inputs2 = (const float*)d_in[1];
  const float* Wq = (const float*)d_in[2];
  const float* bq = (const float*)d_in[3];
  const float* Wk = (const float*)d_in[4];
  const float* bk = (const float*)d_in[5];
  const float* Wv = (const float*)d_in[6];
  const float* bv = (const float*)d_in[7];
  const float* posb = (const float*)d_in[8];
  float* out = (float*)d_out;

  // workspace layout
  char* ws = (char*)d_ws;
  const long long szX  = (long long)ROWS * D_MODEL * 2;            // 16.78 MB
  const long long szW  = (long long)D_MODEL * D_MODEL * 2;         // 0.52 MB
  const long long szEB = (long long)SEQ * SEQ * 2;                 // 8.39 MB
  const long long szT  = (long long)BATCH * 2 * D_MODEL * SEQ * 2; // 33.55 MB
  __bf16* x1b   = (__bf16*)(ws);                 ws += szX;
  __bf16* x2b   = (__bf16*)(ws);                 ws += szX;
  __bf16* wqk   = (__bf16*)(ws);                 ws += 2 * szW;
  __bf16* wvb   = (__bf16*)(ws);                 ws += szW;
  float*  bqk   = (float*)(ws);                  ws += 2 * D_MODEL * 4;
  __bf16* expBb = (__bf16*)(ws);                 ws += szEB;
  __bf16* sigq  = (__bf16*)(ws);                 ws += szX;
  __bf16* kb2   = (__bf16*)(ws);                 ws += szX;
  __bf16* vb2   = (__bf16*)(ws);                 ws += szX;
  __bf16* ekvT  = (__bf16*)(ws);                 ws += szT;

  const int nX  = ROWS * D_MODEL;      // 8388608
  const int nW  = D_MODEL * D_MODEL;   // 262144
  const int nEB = SEQ * SEQ;           // 4194304

  // 1) converts (batched by blockIdx.y)
  {
    dim3 g(nX / 4 / 256, 2, 1);
    cvt_x_kernel<<<g, 256, 0, stream>>>(inputs1, inputs2, x1b, x2b, nX / 4);
  }
  {
    dim3 g(nW / 4 / 256, 3, 1);
    cvt_w_kernel<<<g, 256, 0, stream>>>(Wq, Wk, Wv, bq, bk, wqk, wvb, bqk, nW / 4);
  }
  exp_bf16x4_kernel<<<nEB / 4 / 256, 256, 0, stream>>>(posb, expBb, nEB / 4);

  // 2) projections: qk fused [16384,512]x[1024,512]^T ; v [16384,512]x[512,512]^T
  {
    dim3 gqk(ROWS / 128, (2 * D_MODEL) / 128, 1);
    gemm_bk64_kernel<1><<<gqk, 256, 0, stream>>>(x1b, wqk, bqk, sigq, kb2, D_MODEL);
    dim3 gv(ROWS / 128, D_MODEL / 128, 1);
    gemm_bk64_kernel<0><<<gv, 256, 0, stream>>>(x2b, wvb, bv, vb2, nullptr, D_MODEL);
  }

  // 3) transform + transpose -> ekvT grouped [b][1024][S]
  {
    dim3 g(SEQ / 64, D_MODEL / 64, BATCH);
    dim3 blk(32, 8, 1);
    transform_transpose_kernel<<<g, blk, 0, stream>>>(kb2, vb2, ekvT);
  }

  // 4) einsum + final fused: per batch [2048,2048]x[1024,2048]^T -> out fp32
  {
    dim3 g(SEQ / 128, (2 * D_MODEL) / 128, BATCH);
    einsum_fused_kernel<<<g, 256, 0, stream>>>(expBb, ekvT, sigq, out);
  }
}

// Round 4
// 273.144 us; speedup vs baseline: 1.5517x; 1.0146x over previous
//
#include <hip/hip_runtime.h>

typedef float  f32x4  __attribute__((ext_vector_type(4)));
typedef __bf16 bf16x8 __attribute__((ext_vector_type(8)));
typedef __bf16 bf16x4 __attribute__((ext_vector_type(4)));

#define D_MODEL 512
#define SEQ     2048
#define BATCH   8
#define ROWS    (BATCH * SEQ)   // 16384

// async 16B global -> LDS (each lane deposits at lds_base + lane*16B)
#define ASYNC_COPY16(dst_lds, src_glb)                                          \
  __builtin_amdgcn_global_load_lds(                                             \
      (const __attribute__((address_space(1))) void*)(src_glb),                 \
      (__attribute__((address_space(3))) void*)(dst_lds), 16, 0, 0)

// ------------------------------------------------------------ fused converts
// y=0: x1->x1b  y=1: x2->x2b  y=2: exp(posb)->expBb  y=3: Wq|Wk|Wv->wb
__global__ void cvt_all_kernel(const float* __restrict__ x1,
                               const float* __restrict__ x2,
                               const float* __restrict__ posb,
                               const float* __restrict__ Wq,
                               const float* __restrict__ Wk,
                               const float* __restrict__ Wv,
                               __bf16* __restrict__ x1b, __bf16* __restrict__ x2b,
                               __bf16* __restrict__ expBb, __bf16* __restrict__ wb)
{
  const int y = blockIdx.y;
  const int i = blockIdx.x * 256 + threadIdx.x;
  if (y == 0) {
    float4 v = ((const float4*)x1)[i];
    bf16x4 o = { (__bf16)v.x, (__bf16)v.y, (__bf16)v.z, (__bf16)v.w };
    ((bf16x4*)x1b)[i] = o;
  } else if (y == 1) {
    float4 v = ((const float4*)x2)[i];
    bf16x4 o = { (__bf16)v.x, (__bf16)v.y, (__bf16)v.z, (__bf16)v.w };
    ((bf16x4*)x2b)[i] = o;
  } else if (y == 2) {
    if (i < SEQ * SEQ / 4) {
      float4 v = ((const float4*)posb)[i];
      bf16x4 o = { (__bf16)__expf(v.x), (__bf16)__expf(v.y),
                   (__bf16)__expf(v.z), (__bf16)__expf(v.w) };
      ((bf16x4*)expBb)[i] = o;
    }
  } else {
    const int nW4 = D_MODEL * D_MODEL / 4;
    if (i < 3 * nW4) {
      const float* src = (i < nW4) ? Wq : (i < 2 * nW4) ? Wk : Wv;
      const int ii = i - ((i < nW4) ? 0 : (i < 2 * nW4) ? nW4 : 2 * nW4);
      float4 v = ((const float4*)src)[ii];
      bf16x4 o = { (__bf16)v.x, (__bf16)v.y, (__bf16)v.z, (__bf16)v.w };
      ((bf16x4*)wb)[i] = o;
    }
  }
}

// ------------------------------------------------------------- projections
// z=0: q = sigmoid(x1*Wq^T + bq) -> sigq [ROWS][512] bf16
// z=1: k = x1*Wk^T + bk, v = x2*Wv^T + bv; ek=exp(k), ekv=ek*v; transposed
//      store to ekvT grouped [BATCH][1024][SEQ]: row g*64+w = ekv(d=g*32+w),
//      row g*64+32+w = ek(same d), s = within-batch row.
// 128x128 tile, BK=64, XOR-swizzled staging (same scheme as einsum kernel).
__global__ __launch_bounds__(256) void proj_kernel(
    const __bf16* __restrict__ x1b, const __bf16* __restrict__ x2b,
    const __bf16* __restrict__ wqb, const __bf16* __restrict__ wkb,
    const __bf16* __restrict__ wvb,
    const float* __restrict__ bq, const float* __restrict__ bk,
    const float* __restrict__ bv,
    __bf16* __restrict__ sigq, __bf16* __restrict__ ekvT)
{
  __shared__ __align__(16) __bf16 S[4][128 * 64];   // 64 KB

  const int tid  = threadIdx.x;
  const int wave = tid >> 6;
  const int lane = tid & 63;
  const int quad = lane >> 4;
  const int l16  = lane & 15;
  const int wm   = (wave >> 1) * 64;
  const int wn   = (wave & 1) * 64;
  const int m0 = blockIdx.x * 128;
  const int n0 = blockIdx.y * 128;
  const int l8r = lane >> 3;
  const int scol = ((lane & 7) ^ l8r) * 8;
  const int K = D_MODEL;

  if (blockIdx.z == 0) {
    // ---------------- q path ----------------
    __bf16* As = S[0];
    __bf16* Bs = S[1];
    const __bf16* ga[4]; const __bf16* gb[4];
    __bf16* la[4]; __bf16* lb[4];
    #pragma unroll
    for (int i = 0; i < 4; ++i) {
      ga[i] = x1b + (long long)(m0 + i * 32 + wave * 8 + l8r) * K + scol;
      gb[i] = wqb + (long long)(n0 + i * 32 + wave * 8 + l8r) * K + scol;
      la[i] = As + (i * 32 + wave * 8) * 64;
      lb[i] = Bs + (i * 32 + wave * 8) * 64;
    }
    f32x4 acc[4][4];
    #pragma unroll
    for (int i = 0; i < 4; ++i)
      #pragma unroll
      for (int j = 0; j < 4; ++j) acc[i][j] = (f32x4){0.f, 0.f, 0.f, 0.f};

    for (int k0 = 0; k0 < K; k0 += 64) {
      #pragma unroll
      for (int i = 0; i < 4; ++i) {
        ASYNC_COPY16(la[i], ga[i] + k0);
        ASYNC_COPY16(lb[i], gb[i] + k0);
      }
      __syncthreads();
      #pragma unroll
      for (int kk = 0; kk < 2; ++kk) {
        const int slot = ((quad + kk * 4) ^ (l16 & 7)) * 8;
        bf16x8 af[4], bfr[4];
        #pragma unroll
        for (int i = 0; i < 4; ++i)
          af[i] = *(const bf16x8*)&As[(wm + i * 16 + l16) * 64 + slot];
        #pragma unroll
        for (int j = 0; j < 4; ++j)
          bfr[j] = *(const bf16x8*)&Bs[(wn + j * 16 + l16) * 64 + slot];
        #pragma unroll
        for (int i = 0; i < 4; ++i)
          #pragma unroll
          for (int j = 0; j < 4; ++j)
            acc[i][j] = __builtin_amdgcn_mfma_f32_16x16x32_bf16(af[i], bfr[j],
                                                                acc[i][j], 0, 0, 0);
      }
      __syncthreads();
    }
    #pragma unroll
    for (int j = 0; j < 4; ++j) {
      const int col = n0 + wn + j * 16 + l16;
      const float bqv = bq[col];
      #pragma unroll
      for (int i = 0; i < 4; ++i)
        #pragma unroll
        for (int r = 0; r < 4; ++r) {
          const int row = m0 + wm + i * 16 + quad * 4 + r;
          float x = acc[i][j][r] + bqv;
          sigq[(long long)row * D_MODEL + col] = (__bf16)(1.f / (1.f + __expf(-x)));
        }
    }
  } else {
    // ---------------- kv path ----------------
    __bf16* A1s = S[0];
    __bf16* A2s = S[1];
    __bf16* Bks = S[2];
    __bf16* Bvs = S[3];
    const __bf16* ga1[4]; const __bf16* ga2[4];
    const __bf16* gbk[4]; const __bf16* gbv[4];
    #pragma unroll
    for (int i = 0; i < 4; ++i) {
      const long long roff = (long long)(i * 32 + wave * 8 + l8r);
      ga1[i] = x1b + (m0 + roff) * K + scol;
      ga2[i] = x2b + (m0 + roff) * K + scol;
      gbk[i] = wkb + (n0 + roff) * K + scol;
      gbv[i] = wvb + (n0 + roff) * K + scol;
    }
    f32x4 acck[4][4], accv[4][4];
    #pragma unroll
    for (int i = 0; i < 4; ++i)
      #pragma unroll
      for (int j = 0; j < 4; ++j) {
        acck[i][j] = (f32x4){0.f, 0.f, 0.f, 0.f};
        accv[i][j] = (f32x4){0.f, 0.f, 0.f, 0.f};
      }

    for (int k0 = 0; k0 < K; k0 += 64) {
      #pragma unroll
      for (int i = 0; i < 4; ++i) {
        const int lo = (i * 32 + wave * 8) * 64;
        ASYNC_COPY16(A1s + lo, ga1[i] + k0);
        ASYNC_COPY16(A2s + lo, ga2[i] + k0);
        ASYNC_COPY16(Bks + lo, gbk[i] + k0);
        ASYNC_COPY16(Bvs + lo, gbv[i] + k0);
      }
      __syncthreads();
      #pragma unroll
      for (int kk = 0; kk < 2; ++kk) {
        const int slot = ((quad + kk * 4) ^ (l16 & 7)) * 8;
        bf16x8 af[4], bfr[4];
        // k: x1 * Wk
        #pragma unroll
        for (int i = 0; i < 4; ++i)
          af[i] = *(const bf16x8*)&A1s[(wm + i * 16 + l16) * 64 + slot];
        #pragma unroll
        for (int j = 0; j < 4; ++j)
          bfr[j] = *(const bf16x8*)&Bks[(wn + j * 16 + l16) * 64 + slot];
        #pragma unroll
        for (int i = 0; i < 4; ++i)
          #pragma unroll
          for (int j = 0; j < 4; ++j)
            acck[i][j] = __builtin_amdgcn_mfma_f32_16x16x32_bf16(af[i], bfr[j],
                                                                 acck[i][j], 0, 0, 0);
        // v: x2 * Wv
        #pragma unroll
        for (int i = 0; i < 4; ++i)
          af[i] = *(const bf16x8*)&A2s[(wm + i * 16 + l16) * 64 + slot];
        #pragma unroll
        for (int j = 0; j < 4; ++j)
          bfr[j] = *(const bf16x8*)&Bvs[(wn + j * 16 + l16) * 64 + slot];
        #pragma unroll
        for (int i = 0; i < 4; ++i)
          #pragma unroll
          for (int j = 0; j < 4; ++j)
            accv[i][j] = __builtin_amdgcn_mfma_f32_16x16x32_bf16(af[i], bfr[j],
                                                                 accv[i][j], 0, 0, 0);
      }
      __syncthreads();
    }

    // epilogue: ek/ekv -> LDS transposed (16B-chunk XOR swizzle) -> ekvT
    // LDS view: 256 rows x 128 s-cols; row R, s-chunk c stored at
    // elem offset R*128 + ((c ^ (R&15))<<3) + (s&7)
    __bf16* L = &S[0][0];
    #pragma unroll
    for (int j = 0; j < 4; ++j) {
      const int col = wn + j * 16 + l16;          // 0..127 local d
      const float bkv = bk[n0 + col];
      const float bvv = bv[n0 + col];
      const int Rekv = (col >> 5) * 64 + (col & 31);
      const int Rek  = Rekv + 32;
      #pragma unroll
      for (int i = 0; i < 4; ++i) {
        const int sb = wm + i * 16 + quad * 4;    // s local, multiple of 4
        bf16x4 pk, pv;
        #pragma unroll
        for (int r = 0; r < 4; ++r) {
          const float ek = __expf(acck[i][j][r] + bkv);
          const float vv = accv[i][j][r] + bvv;
          pk[r] = (__bf16)ek;
          pv[r] = (__bf16)(ek * vv);
        }
        const int c = sb >> 3, w8 = sb & 7;
        *(bf16x4*)&L[Rekv * 128 + (((c) ^ (Rekv & 15)) << 3) + w8] = pv;
        *(bf16x4*)&L[Rek  * 128 + (((c) ^ (Rek  & 15)) << 3) + w8] = pk;
      }
    }
    __syncthreads();

    const long long obase = (long long)(m0 >> 11) * (2 * D_MODEL) * SEQ
                          + (long long)(m0 & (SEQ - 1));
    #pragma unroll
    for (int ii = 0; ii < 16; ++ii) {
      const int flat = ii * 256 + tid;            // 0..4095
      const int R = flat >> 4;
      const int c = flat & 15;
      bf16x8 vv = *(const bf16x8*)&L[R * 128 + ((c ^ (R & 15)) << 3)];
      *(bf16x8*)(ekvT + obase + (long long)(blockIdx.y * 256 + R) * SEQ + c * 8) = vv;
    }
  }
}

// -------------------------------------------- einsum + final, fused epilogue
// A = expB [2048][2048]; Bt = ekvT grouped [BATCH][1024][2048].
// acc[i][j] j<2 = num(d), acc[i][j+2] = den(same d).
// out[b*SEQ+t][d] = sigq * num/den  (fp32, written directly).
__global__ __launch_bounds__(256) void einsum_fused_kernel(
    const __bf16* __restrict__ A, const __bf16* __restrict__ BtAll,
    const __bf16* __restrict__ sigq, float* __restrict__ out)
{
  __shared__ __align__(16) __bf16 As[128 * 64];
  __shared__ __align__(16) __bf16 Bs[128 * 64];

  const int b = blockIdx.z;
  const __bf16* Bt = BtAll + (long long)b * (2 * D_MODEL) * SEQ;
  const int K = SEQ;

  const int tid  = threadIdx.x;
  const int wave = tid >> 6;
  const int lane = tid & 63;
  const int quad = lane >> 4;
  const int l16  = lane & 15;
  const int wm   = (wave >> 1) * 64;
  const int wn   = (wave & 1) * 64;
  const int m0 = blockIdx.x * 128;
  const int n0 = blockIdx.y * 128;
  const int l8r = lane >> 3;
  const int scol = ((lane & 7) ^ l8r) * 8;

  const __bf16* ga[4]; const __bf16* gb[4];
  __bf16* la[4]; __bf16* lb[4];
  #pragma unroll
  for (int i = 0; i < 4; ++i) {
    ga[i] = A  + (long long)(m0 + i * 32 + wave * 8 + l8r) * K + scol;
    gb[i] = Bt + (long long)(n0 + i * 32 + wave * 8 + l8r) * K + scol;
    la[i] = As + (i * 32 + wave * 8) * 64;
    lb[i] = Bs + (i * 32 + wave * 8) * 64;
  }

  f32x4 acc[4][4];
  #pragma unroll
  for (int i = 0; i < 4; ++i)
    #pragma unroll
    for (int j = 0; j < 4; ++j) acc[i][j] = (f32x4){0.f, 0.f, 0.f, 0.f};

  for (int k0 = 0; k0 < K; k0 += 64) {
    #pragma unroll
    for (int i = 0; i < 4; ++i) {
      ASYNC_COPY16(la[i], ga[i] + k0);
      ASYNC_COPY16(lb[i], gb[i] + k0);
    }
    __syncthreads();

    #pragma unroll
    for (int kk = 0; kk < 2; ++kk) {
      const int slot = ((quad + kk * 4) ^ (l16 & 7)) * 8;
      bf16x8 af[4], bfr[4];
      #pragma unroll
      for (int i = 0; i < 4; ++i)
        af[i] = *(const bf16x8*)&As[(wm + i * 16 + l16) * 64 + slot];
      #pragma unroll
      for (int j = 0; j < 4; ++j)
        bfr[j] = *(const bf16x8*)&Bs[(wn + j * 16 + l16) * 64 + slot];
      #pragma unroll
      for (int i = 0; i < 4; ++i)
        #pragma unroll
        for (int j = 0; j < 4; ++j)
          acc[i][j] = __builtin_amdgcn_mfma_f32_16x16x32_bf16(af[i], bfr[j],
                                                              acc[i][j], 0, 0, 0);
    }
    __syncthreads();
  }

  const int g = (n0 + wn) >> 6;
  #pragma unroll
  for (int j = 0; j < 2; ++j) {
    const int d = g * 32 + j * 16 + l16;
    #pragma unroll
    for (int i = 0; i < 4; ++i) {
      #pragma unroll
      for (int r = 0; r < 4; ++r) {
        const int row = m0 + wm + i * 16 + quad * 4 + r;
        const long long off = ((long long)b * SEQ + row) * D_MODEL + d;
        const float num = acc[i][j][r];
        const float den = acc[i][j + 2][r];
        out[off] = (float)sigq[off] * (num / den);
      }
    }
  }
}

// ---------------------------------------------------------------- launch
extern "C" void kernel_launch(void* const* d_in, const int* in_sizes, int n_in,
                              void* d_out, int out_size, void* d_ws, size_t ws_size,
                              hipStream_t stream) {
  const float* inputs1 = (const float*)d_in[0];
  const float* inputs2 = (const float*)d_in[1];
  const float* Wq = (const float*)d_in[2];
  const float* bq = (const float*)d_in[3];
  const float* Wk = (const float*)d_in[4];
  const float* bk = (const float*)d_in[5];
  const float* Wv = (const float*)d_in[6];
  const float* bv = (const float*)d_in[7];
  const float* posb = (const float*)d_in[8];
  float* out = (float*)d_out;

  // workspace layout
  char* ws = (char*)d_ws;
  const long long szX  = (long long)ROWS * D_MODEL * 2;            // 16.78 MB
  const long long szW  = (long long)D_MODEL * D_MODEL * 2;         // 0.52 MB
  const long long szEB = (long long)SEQ * SEQ * 2;                 // 8.39 MB
  const long long szT  = (long long)BATCH * 2 * D_MODEL * SEQ * 2; // 33.55 MB
  __bf16* x1b   = (__bf16*)(ws);                 ws += szX;
  __bf16* x2b   = (__bf16*)(ws);                 ws += szX;
  __bf16* wb    = (__bf16*)(ws);                 ws += 3 * szW;
  __bf16* expBb = (__bf16*)(ws);                 ws += szEB;
  __bf16* sigq  = (__bf16*)(ws);                 ws += szX;
  __bf16* ekvT  = (__bf16*)(ws);                 ws += szT;
  __bf16* wqb = wb;
  __bf16* wkb = wb + (long long)D_MODEL * D_MODEL;
  __bf16* wvb = wb + 2LL * D_MODEL * D_MODEL;

  const int nX = ROWS * D_MODEL;   // 8388608

  // 1) all converts, one launch
  {
    dim3 g(nX / 4 / 256, 4, 1);
    cvt_all_kernel<<<g, 256, 0, stream>>>(inputs1, inputs2, posb, Wq, Wk, Wv,
                                          x1b, x2b, expBb, wb);
  }

  // 2) projections: z=0 q->sigq, z=1 kv->ekvT (fused exp/mul/transpose)
  {
    dim3 g(ROWS / 128, D_MODEL / 128, 2);
    proj_kernel<<<g, 256, 0, stream>>>(x1b, x2b, wqb, wkb, wvb,
                                       bq, bk, bv, sigq, ekvT);
  }

  // 3) einsum + final fused: per batch [2048,2048]x[1024,2048]^T -> out fp32
  {
    dim3 g(SEQ / 128, (2 * D_MODEL) / 128, BATCH);
    einsum_fused_kernel<<<g, 256, 0, stream>>>(expBb, ekvT, sigq, out);
  }
}

// Round 5
// 270.502 us; speedup vs baseline: 1.5669x; 1.0098x over previous
//
#include <hip/hip_runtime.h>

typedef float  f32x4  __attribute__((ext_vector_type(4)));
typedef __bf16 bf16x8 __attribute__((ext_vector_type(8)));
typedef __bf16 bf16x4 __attribute__((ext_vector_type(4)));
typedef __bf16 bf16x2 __attribute__((ext_vector_type(2)));

#define D_MODEL 512
#define SEQ     2048
#define BATCH   8
#define ROWS    (BATCH * SEQ)   // 16384

// async 16B global -> LDS (each lane deposits at lds_base + lane*16B)
#define ASYNC_COPY16(dst_lds, src_glb)                                          \
  __builtin_amdgcn_global_load_lds(                                             \
      (const __attribute__((address_space(1))) void*)(src_glb),                 \
      (__attribute__((address_space(3))) void*)(dst_lds), 16, 0, 0)

// ------------------------------------------------------------ fused converts
// flat 1D grid, exact ranges:
// [0,8192)        x1 -> x1b
// [8192,16384)    x2 -> x2b
// [16384,20480)   exp(posb) -> expBb
// [20480,21248)   Wq|Wk|Wv -> wb
// [21248,21254)   bq|bk|bv -> bcat (fp32)
__global__ void cvt_all_kernel(const float* __restrict__ x1,
                               const float* __restrict__ x2,
                               const float* __restrict__ posb,
                               const float* __restrict__ Wq,
                               const float* __restrict__ Wk,
                               const float* __restrict__ Wv,
                               const float* __restrict__ bq,
                               const float* __restrict__ bk,
                               const float* __restrict__ bv,
                               __bf16* __restrict__ x1b, __bf16* __restrict__ x2b,
                               __bf16* __restrict__ expBb, __bf16* __restrict__ wb,
                               float* __restrict__ bcat)
{
  const int blk = blockIdx.x;
  if (blk < 16384) {
    const float* in = (blk < 8192) ? x1 : x2;
    __bf16* out = (blk < 8192) ? x1b : x2b;
    const int i = (blk & 8191) * 256 + threadIdx.x;
    float4 v = ((const float4*)in)[i];
    bf16x4 o = { (__bf16)v.x, (__bf16)v.y, (__bf16)v.z, (__bf16)v.w };
    ((bf16x4*)out)[i] = o;
  } else if (blk < 20480) {
    const int i = (blk - 16384) * 256 + threadIdx.x;
    float4 v = ((const float4*)posb)[i];
    bf16x4 o = { (__bf16)__expf(v.x), (__bf16)__expf(v.y),
                 (__bf16)__expf(v.z), (__bf16)__expf(v.w) };
    ((bf16x4*)expBb)[i] = o;
  } else if (blk < 21248) {
    const int i = (blk - 20480) * 256 + threadIdx.x;   // 0 .. 196607 quads
    const int nW4 = D_MODEL * D_MODEL / 4;
    const float* src = (i < nW4) ? Wq : (i < 2 * nW4) ? Wk : Wv;
    const int ii = i - ((i < nW4) ? 0 : (i < 2 * nW4) ? nW4 : 2 * nW4);
    float4 v = ((const float4*)src)[ii];
    bf16x4 o = { (__bf16)v.x, (__bf16)v.y, (__bf16)v.z, (__bf16)v.w };
    ((bf16x4*)wb)[i] = o;
  } else {
    const int t = (blk - 21248) * 256 + threadIdx.x;   // 0..1535
    float v = (t < 512) ? bq[t] : (t < 1024) ? bk[t - 512] : bv[t - 1024];
    bcat[t] = v;
  }
}

// ------------------------------------------------------------- QKV GEMM
// C[16384,1536] = A*[Wq;Wk;Wv]^T + bcat; A = x1b for cols<1024, x2b else.
// Epilogue: col<512 -> sigmoid -> sigq ; col<1024 -> kb ; else -> vb.
// 128x128 tile, BK=64, XOR-swizzled staging (same structure as einsum).
__global__ __launch_bounds__(256) void qkv_gemm_kernel(
    const __bf16* __restrict__ x1b, const __bf16* __restrict__ x2b,
    const __bf16* __restrict__ wb, const float* __restrict__ bcat,
    __bf16* __restrict__ sigq, __bf16* __restrict__ kb,
    __bf16* __restrict__ vb)
{
  __shared__ __align__(16) __bf16 As[128 * 64];
  __shared__ __align__(16) __bf16 Bs[128 * 64];

  const int K = D_MODEL;
  const int tid  = threadIdx.x;
  const int wave = tid >> 6;
  const int lane = tid & 63;
  const int quad = lane >> 4;
  const int l16  = lane & 15;
  const int wm   = (wave >> 1) * 64;
  const int wn   = (wave & 1) * 64;
  const int m0 = blockIdx.x * 128;
  const int n0 = blockIdx.y * 128;          // 0..1535 (global row into wb)
  const int l8r = lane >> 3;
  const int scol = ((lane & 7) ^ l8r) * 8;

  const __bf16* A = (blockIdx.y < 8) ? x1b : x2b;

  const __bf16* ga[4]; const __bf16* gb[4];
  __bf16* la[4]; __bf16* lb[4];
  #pragma unroll
  for (int i = 0; i < 4; ++i) {
    ga[i] = A  + (long long)(m0 + i * 32 + wave * 8 + l8r) * K + scol;
    gb[i] = wb + (long long)(n0 + i * 32 + wave * 8 + l8r) * K + scol;
    la[i] = As + (i * 32 + wave * 8) * 64;
    lb[i] = Bs + (i * 32 + wave * 8) * 64;
  }

  f32x4 acc[4][4];
  #pragma unroll
  for (int i = 0; i < 4; ++i)
    #pragma unroll
    for (int j = 0; j < 4; ++j) acc[i][j] = (f32x4){0.f, 0.f, 0.f, 0.f};

  for (int k0 = 0; k0 < K; k0 += 64) {
    #pragma unroll
    for (int i = 0; i < 4; ++i) {
      ASYNC_COPY16(la[i], ga[i] + k0);
      ASYNC_COPY16(lb[i], gb[i] + k0);
    }
    __syncthreads();
    #pragma unroll
    for (int kk = 0; kk < 2; ++kk) {
      const int slot = ((quad + kk * 4) ^ (l16 & 7)) * 8;
      bf16x8 af[4], bfr[4];
      #pragma unroll
      for (int i = 0; i < 4; ++i)
        af[i] = *(const bf16x8*)&As[(wm + i * 16 + l16) * 64 + slot];
      #pragma unroll
      for (int j = 0; j < 4; ++j)
        bfr[j] = *(const bf16x8*)&Bs[(wn + j * 16 + l16) * 64 + slot];
      #pragma unroll
      for (int i = 0; i < 4; ++i)
        #pragma unroll
        for (int j = 0; j < 4; ++j)
          acc[i][j] = __builtin_amdgcn_mfma_f32_16x16x32_bf16(af[i], bfr[j],
                                                              acc[i][j], 0, 0, 0);
    }
    __syncthreads();
  }

  // epilogue: C/D layout col = lane&15, row = quad*4 + reg
  #pragma unroll
  for (int j = 0; j < 4; ++j) {
    const int col = n0 + wn + j * 16 + l16;   // 0..1535
    const float bvv = bcat[col];
    #pragma unroll
    for (int i = 0; i < 4; ++i) {
      #pragma unroll
      for (int r = 0; r < 4; ++r) {
        const int row = m0 + wm + i * 16 + quad * 4 + r;
        float x = acc[i][j][r] + bvv;
        if (col < D_MODEL) {
          sigq[(long long)row * D_MODEL + col] = (__bf16)(1.f / (1.f + __expf(-x)));
        } else if (col < 2 * D_MODEL) {
          kb[(long long)row * D_MODEL + (col - D_MODEL)] = (__bf16)x;
        } else {
          vb[(long long)row * D_MODEL + (col - 2 * D_MODEL)] = (__bf16)x;
        }
      }
    }
  }
}

// ------------------------------------------------- transform + transpose
// in : kb,vb [BATCH][SEQ][D] bf16; out: ekvT grouped [BATCH][1024][SEQ]:
// for d: g=d>>5, w=d&31: row g*64+w = exp(k)*v, row g*64+32+w = exp(k)
__global__ __launch_bounds__(256) void transform_transpose_kernel(
    const __bf16* __restrict__ kb, const __bf16* __restrict__ vb,
    __bf16* __restrict__ ekvT)
{
  __shared__ float t_ekv[64][67];
  __shared__ float t_ek[64][67];
  const int b  = blockIdx.z;
  const int s0 = blockIdx.x * 64;
  const int d0 = blockIdx.y * 64;
  const int tx = threadIdx.x;   // 0..31
  const int ty = threadIdx.y;   // 0..7
  const __bf16* kp = kb + (long long)b * SEQ * D_MODEL;
  const __bf16* vp = vb + (long long)b * SEQ * D_MODEL;

  #pragma unroll
  for (int it = 0; it < 8; ++it) {
    const int sl = ty + it * 8;               // local s row 0..63
    const long long base = (long long)(s0 + sl) * D_MODEL + d0 + 2 * tx;
    bf16x2 kk2 = *(const bf16x2*)(kp + base);
    bf16x2 vv2 = *(const bf16x2*)(vp + base);
    float e0 = __expf((float)kk2[0]);
    float e1 = __expf((float)kk2[1]);
    t_ek[sl][2 * tx]      = e0;
    t_ek[sl][2 * tx + 1]  = e1;
    t_ekv[sl][2 * tx]     = e0 * (float)vv2[0];
    t_ekv[sl][2 * tx + 1] = e1 * (float)vv2[1];
  }
  __syncthreads();

  __bf16* outp = ekvT + (long long)b * (2 * D_MODEL) * SEQ;
  #pragma unroll
  for (int it = 0; it < 8; ++it) {
    const int dl = ty + it * 8;               // local d 0..63
    const int d  = d0 + dl;
    const int gr = (d >> 5) * 64 + (d & 31);  // grouped ekv row
    bf16x2 ev = { (__bf16)t_ekv[2 * tx][dl], (__bf16)t_ekv[2 * tx + 1][dl] };
    bf16x2 ee = { (__bf16)t_ek[2 * tx][dl],  (__bf16)t_ek[2 * tx + 1][dl] };
    *(bf16x2*)(outp + (long long)gr * SEQ + s0 + 2 * tx)        = ev;
    *(bf16x2*)(outp + (long long)(gr + 32) * SEQ + s0 + 2 * tx) = ee;
  }
}

// -------------------------------------------- einsum + final, fused epilogue
// A = expB [2048][2048]; Bt = ekvT grouped [BATCH][1024][2048].
// acc[i][j] j<2 = num(d), acc[i][j+2] = den(same d).
// out[b*SEQ+t][d] = sigq * num/den  (fp32, written directly).
__global__ __launch_bounds__(256) void einsum_fused_kernel(
    const __bf16* __restrict__ A, const __bf16* __restrict__ BtAll,
    const __bf16* __restrict__ sigq, float* __restrict__ out)
{
  __shared__ __align__(16) __bf16 As[128 * 64];
  __shared__ __align__(16) __bf16 Bs[128 * 64];

  const int b = blockIdx.z;
  const __bf16* Bt = BtAll + (long long)b * (2 * D_MODEL) * SEQ;
  const int K = SEQ;

  const int tid  = threadIdx.x;
  const int wave = tid >> 6;
  const int lane = tid & 63;
  const int quad = lane >> 4;
  const int l16  = lane & 15;
  const int wm   = (wave >> 1) * 64;
  const int wn   = (wave & 1) * 64;
  const int m0 = blockIdx.x * 128;
  const int n0 = blockIdx.y * 128;
  const int l8r = lane >> 3;
  const int scol = ((lane & 7) ^ l8r) * 8;

  const __bf16* ga[4]; const __bf16* gb[4];
  __bf16* la[4]; __bf16* lb[4];
  #pragma unroll
  for (int i = 0; i < 4; ++i) {
    ga[i] = A  + (long long)(m0 + i * 32 + wave * 8 + l8r) * K + scol;
    gb[i] = Bt + (long long)(n0 + i * 32 + wave * 8 + l8r) * K + scol;
    la[i] = As + (i * 32 + wave * 8) * 64;
    lb[i] = Bs + (i * 32 + wave * 8) * 64;
  }

  f32x4 acc[4][4];
  #pragma unroll
  for (int i = 0; i < 4; ++i)
    #pragma unroll
    for (int j = 0; j < 4; ++j) acc[i][j] = (f32x4){0.f, 0.f, 0.f, 0.f};

  for (int k0 = 0; k0 < K; k0 += 64) {
    #pragma unroll
    for (int i = 0; i < 4; ++i) {
      ASYNC_COPY16(la[i], ga[i] + k0);
      ASYNC_COPY16(lb[i], gb[i] + k0);
    }
    __syncthreads();

    #pragma unroll
    for (int kk = 0; kk < 2; ++kk) {
      const int slot = ((quad + kk * 4) ^ (l16 & 7)) * 8;
      bf16x8 af[4], bfr[4];
      #pragma unroll
      for (int i = 0; i < 4; ++i)
        af[i] = *(const bf16x8*)&As[(wm + i * 16 + l16) * 64 + slot];
      #pragma unroll
      for (int j = 0; j < 4; ++j)
        bfr[j] = *(const bf16x8*)&Bs[(wn + j * 16 + l16) * 64 + slot];
      #pragma unroll
      for (int i = 0; i < 4; ++i)
        #pragma unroll
        for (int j = 0; j < 4; ++j)
          acc[i][j] = __builtin_amdgcn_mfma_f32_16x16x32_bf16(af[i], bfr[j],
                                                              acc[i][j], 0, 0, 0);
    }
    __syncthreads();
  }

  const int g = (n0 + wn) >> 6;
  #pragma unroll
  for (int j = 0; j < 2; ++j) {
    const int d = g * 32 + j * 16 + l16;
    #pragma unroll
    for (int i = 0; i < 4; ++i) {
      #pragma unroll
      for (int r = 0; r < 4; ++r) {
        const int row = m0 + wm + i * 16 + quad * 4 + r;
        const long long off = ((long long)b * SEQ + row) * D_MODEL + d;
        const float num = acc[i][j][r];
        const float den = acc[i][j + 2][r];
        out[off] = (float)sigq[off] * (num / den);
      }
    }
  }
}

// ---------------------------------------------------------------- launch
extern "C" void kernel_launch(void* const* d_in, const int* in_sizes, int n_in,
                              void* d_out, int out_size, void* d_ws, size_t ws_size,
                              hipStream_t stream) {
  const float* inputs1 = (const float*)d_in[0];
  const float* inputs2 = (const float*)d_in[1];
  const float* Wq = (const float*)d_in[2];
  const float* bq = (const float*)d_in[3];
  const float* Wk = (const float*)d_in[4];
  const float* bk = (const float*)d_in[5];
  const float* Wv = (const float*)d_in[6];
  const float* bv = (const float*)d_in[7];
  const float* posb = (const float*)d_in[8];
  float* out = (float*)d_out;

  // workspace layout
  char* ws = (char*)d_ws;
  const long long szX  = (long long)ROWS * D_MODEL * 2;            // 16.78 MB
  const long long szW  = (long long)D_MODEL * D_MODEL * 2;         // 0.52 MB
  const long long szEB = (long long)SEQ * SEQ * 2;                 // 8.39 MB
  const long long szT  = (long long)BATCH * 2 * D_MODEL * SEQ * 2; // 33.55 MB
  __bf16* x1b   = (__bf16*)(ws);                 ws += szX;
  __bf16* x2b   = (__bf16*)(ws);                 ws += szX;
  __bf16* wb    = (__bf16*)(ws);                 ws += 3 * szW;
  float*  bcat  = (float*)(ws);                  ws += 3 * D_MODEL * 4;
  __bf16* expBb = (__bf16*)(ws);                 ws += szEB;
  __bf16* sigq  = (__bf16*)(ws);                 ws += szX;
  __bf16* kb    = (__bf16*)(ws);                 ws += szX;
  __bf16* vb    = (__bf16*)(ws);                 ws += szX;
  __bf16* ekvT  = (__bf16*)(ws);                 ws += szT;

  // 1) all converts, one flat launch (21254 blocks, exact ranges)
  cvt_all_kernel<<<21254, 256, 0, stream>>>(inputs1, inputs2, posb,
                                            Wq, Wk, Wv, bq, bk, bv,
                                            x1b, x2b, expBb, wb, bcat);

  // 2) QKV GEMM: [16384,512] x [1536,512]^T, epilogue-routed
  {
    dim3 g(ROWS / 128, (3 * D_MODEL) / 128, 1);
    qkv_gemm_kernel<<<g, 256, 0, stream>>>(x1b, x2b, wb, bcat, sigq, kb, vb);
  }

  // 3) transform + transpose -> ekvT grouped [b][1024][S]
  {
    dim3 g(SEQ / 64, D_MODEL / 64, BATCH);
    dim3 blk(32, 8, 1);
    transform_transpose_kernel<<<g, blk, 0, stream>>>(kb, vb, ekvT);
  }

  // 4) einsum + final fused: per batch [2048,2048]x[1024,2048]^T -> out fp32
  {
    dim3 g(SEQ / 128, (2 * D_MODEL) / 128, BATCH);
    einsum_fused_kernel<<<g, 256, 0, stream>>>(expBb, ekvT, sigq, out);
  }
}